// Round 1
// baseline (819.461 us; speedup 1.0000x reference)
//
#include <hip/hip_runtime.h>

#define NN 4096
#define NFEAT 512
#define NHID 64
#define H1 8
#define NCLS 16
#define NEG_SLOPE 0.2f
#define MASK_VAL -1e10f

__device__ __forceinline__ float leaky(float v) { return v > 0.f ? v : NEG_SLOPE * v; }

// ---------------------------------------------------------------------------
// Kernel A: feats1[h][r][c] = sum_k x[r][k] * W1[h][k][c];  s1/nb1 = feats1 . a
// grid (256 row-tiles, 8 heads), 256 threads. 16 rows per block.
// ---------------------------------------------------------------------------
__global__ __launch_bounds__(256)
void k_feats1(const float* __restrict__ x, const float* __restrict__ W1,
              const float* __restrict__ as1, const float* __restrict__ an1,
              float* __restrict__ feats1, float* __restrict__ s1, float* __restrict__ nb1)
{
    __shared__ float xs[16][NFEAT];   // 32 KB
    __shared__ float fs[16][NHID];    // 4 KB
    const int t = threadIdx.x;
    const int rt = blockIdx.x, h = blockIdx.y;
    const int R0 = rt * 16;

    {   // stage 16x512 x-tile, coalesced float4
        const float4* xg = (const float4*)(x + (size_t)R0 * NFEAT);
        float4* xl = (float4*)&xs[0][0];
        #pragma unroll
        for (int i = 0; i < 8; ++i) xl[t + 256 * i] = xg[t + 256 * i];
    }
    __syncthreads();

    const int c  = t & 63;     // output col = lane
    const int wv = t >> 6;     // wave id -> row quad
    const int r0 = wv * 4;
    const float* Wp = W1 + ((size_t)h * NFEAT) * NHID + c;
    float a0 = 0.f, a1 = 0.f, a2 = 0.f, a3 = 0.f;
    for (int k = 0; k < NFEAT; k += 4) {
        const float w0 = Wp[(k + 0) * NHID];
        const float w1 = Wp[(k + 1) * NHID];
        const float w2 = Wp[(k + 2) * NHID];
        const float w3 = Wp[(k + 3) * NHID];
        const float4 x0 = *(const float4*)&xs[r0 + 0][k];
        const float4 x1 = *(const float4*)&xs[r0 + 1][k];
        const float4 x2 = *(const float4*)&xs[r0 + 2][k];
        const float4 x3 = *(const float4*)&xs[r0 + 3][k];
        a0 += x0.x * w0 + x0.y * w1 + x0.z * w2 + x0.w * w3;
        a1 += x1.x * w0 + x1.y * w1 + x1.z * w2 + x1.w * w3;
        a2 += x2.x * w0 + x2.y * w1 + x2.z * w2 + x2.w * w3;
        a3 += x3.x * w0 + x3.y * w1 + x3.z * w2 + x3.w * w3;
    }
    float* fout = feats1 + ((size_t)h * NN + R0 + r0) * NHID + c;
    fout[0 * NHID] = a0; fout[1 * NHID] = a1; fout[2 * NHID] = a2; fout[3 * NHID] = a3;
    fs[r0 + 0][c] = a0; fs[r0 + 1][c] = a1; fs[r0 + 2][c] = a2; fs[r0 + 3][c] = a3;
    __syncthreads();

    // s1/nb1: one wave per row, 64-lane shuffle reduce
    const float vas = as1[h * NHID + c];
    const float van = an1[h * NHID + c];
    for (int rr = wv; rr < 16; rr += 4) {
        const float f = fs[rr][c];
        float ps = f * vas, pn = f * van;
        #pragma unroll
        for (int off = 32; off > 0; off >>= 1) {
            ps += __shfl_xor(ps, off, 64);
            pn += __shfl_xor(pn, off, 64);
        }
        if (c == 0) { s1[h * NN + R0 + rr] = ps; nb1[h * NN + R0 + rr] = pn; }
    }
}

// ---------------------------------------------------------------------------
// Kernel B: flash-style masked-softmax aggregation per head.
// grid (256 row-tiles, 8 heads), 256 threads = 16 rows x 16 col-quads.
// hcat[row][h*64 + c] = relu( (sum_j p_ij * feats1[h][j][c]) / l_i + b1[h][c] )
// (elu after relu is identity on >=0, so it is folded away)
// ---------------------------------------------------------------------------
__global__ __launch_bounds__(256)
void k_gat1(const float* __restrict__ feats1, const float* __restrict__ s1,
            const float* __restrict__ nb1, const int* __restrict__ adj,
            const float* __restrict__ b1, float* __restrict__ hcat)
{
    __shared__ float fv[64][NHID];   // 16 KB  V-tile
    __shared__ float pv[16][72];     // padded: banks (8r+jj)%32 distinct
    __shared__ float nbs[64];
    const int t = threadIdx.x;
    const int rt = blockIdx.x, h = blockIdx.y;
    const int R0 = rt * 16;
    const int r = t >> 4, cq = t & 15;
    const int row = R0 + r;
    const float s_r = s1[h * NN + row];
    const int* adjp = adj + (size_t)row * NN;
    const float* fbase = feats1 + (size_t)h * NN * NHID;
    const float* nbase = nb1 + h * NN;

    float m = -INFINITY, l = 0.f;
    float a0 = 0.f, a1 = 0.f, a2 = 0.f, a3 = 0.f;

    for (int j0 = 0; j0 < NN; j0 += 64) {
        if (t < 64) nbs[t] = nbase[j0 + t];
        {   // V tile 64x64, coalesced float4
            const float4* fg = (const float4*)(fbase + (size_t)j0 * NHID);
            float4* fl = (float4*)&fv[0][0];
            #pragma unroll
            for (int i = 0; i < 4; ++i) fl[t + 256 * i] = fg[t + 256 * i];
        }
        __syncthreads();

        const int4 av = *(const int4*)(adjp + j0 + cq * 4);
        const float v0 = (av.x > 0) ? leaky(s_r + nbs[cq * 4 + 0]) : MASK_VAL;
        const float v1 = (av.y > 0) ? leaky(s_r + nbs[cq * 4 + 1]) : MASK_VAL;
        const float v2 = (av.z > 0) ? leaky(s_r + nbs[cq * 4 + 2]) : MASK_VAL;
        const float v3 = (av.w > 0) ? leaky(s_r + nbs[cq * 4 + 3]) : MASK_VAL;

        float cmax = fmaxf(fmaxf(v0, v1), fmaxf(v2, v3));
        #pragma unroll
        for (int off = 8; off > 0; off >>= 1) cmax = fmaxf(cmax, __shfl_xor(cmax, off, 64));
        const float nm = fmaxf(m, cmax);
        const float alpha = __expf(m - nm);
        const float p0 = __expf(v0 - nm), p1 = __expf(v1 - nm);
        const float p2 = __expf(v2 - nm), p3 = __expf(v3 - nm);
        float cs = p0 + p1 + p2 + p3;
        #pragma unroll
        for (int off = 8; off > 0; off >>= 1) cs += __shfl_xor(cs, off, 64);
        l = l * alpha + cs;
        m = nm;
        a0 *= alpha; a1 *= alpha; a2 *= alpha; a3 *= alpha;
        *(float4*)&pv[r][cq * 4] = make_float4(p0, p1, p2, p3);
        __syncthreads();

        #pragma unroll 16
        for (int jj = 0; jj < 64; ++jj) {
            const float p = pv[r][jj];
            const float4 f = *(const float4*)&fv[jj][cq * 4];
            a0 += p * f.x; a1 += p * f.y; a2 += p * f.z; a3 += p * f.w;
        }
        __syncthreads();
    }

    const float inv = 1.f / l;
    const float4 bb = *(const float4*)&b1[h * NHID + cq * 4];
    const float o0 = fmaxf(a0 * inv + bb.x, 0.f);
    const float o1 = fmaxf(a1 * inv + bb.y, 0.f);
    const float o2 = fmaxf(a2 * inv + bb.z, 0.f);
    const float o3 = fmaxf(a3 * inv + bb.w, 0.f);
    *(float4*)&hcat[(size_t)row * (H1 * NHID) + h * NHID + cq * 4] = make_float4(o0, o1, o2, o3);
}

// ---------------------------------------------------------------------------
// Kernel C1: feats2 = hcat @ W2 (+ s2/nb2). grid 256, 256 threads, 16 rows/blk
// ---------------------------------------------------------------------------
__global__ __launch_bounds__(256)
void k_feats2(const float* __restrict__ hcat, const float* __restrict__ W2,
              const float* __restrict__ as2, const float* __restrict__ an2,
              float* __restrict__ feats2, float* __restrict__ s2, float* __restrict__ nb2)
{
    __shared__ float hs[16][520];        // padded stride: banks (8r+k)%32
    __shared__ float w2s[NFEAT][NCLS];
    __shared__ float fs2[16][NCLS];
    const int t = threadIdx.x;
    const int R0 = blockIdx.x * 16;

    {
        const float4* hg = (const float4*)(hcat + (size_t)R0 * (H1 * NHID));
        #pragma unroll
        for (int i = 0; i < 8; ++i) {
            const int idx = t + 256 * i;        // float4 index 0..2047
            const int rr = idx >> 7, col = idx & 127;
            *(float4*)&hs[rr][col * 4] = hg[idx];
        }
        const float4* wg = (const float4*)W2;
        float4* wl = (float4*)&w2s[0][0];
        #pragma unroll
        for (int i = 0; i < 8; ++i) wl[t + 256 * i] = wg[t + 256 * i];
    }
    __syncthreads();

    const int r = t >> 4, c = t & 15;
    float acc = 0.f;
    #pragma unroll 8
    for (int k = 0; k < NFEAT; ++k) acc += hs[r][k] * w2s[k][c];
    feats2[(R0 + r) * NCLS + c] = acc;
    fs2[r][c] = acc;
    __syncthreads();

    if (t < 16) {
        float ss = 0.f, sn = 0.f;
        #pragma unroll
        for (int cc = 0; cc < NCLS; ++cc) { ss += fs2[t][cc] * as2[cc]; sn += fs2[t][cc] * an2[cc]; }
        s2[R0 + t] = ss; nb2[R0 + t] = sn;
    }
}

// ---------------------------------------------------------------------------
// Kernel C2: layer-2 aggregation + relu + log_softmax over 16 classes.
// grid 256, 256 threads = 16 rows x 16 classes.
// ---------------------------------------------------------------------------
__global__ __launch_bounds__(256)
void k_gat2(const float* __restrict__ feats2, const float* __restrict__ s2,
            const float* __restrict__ nb2, const int* __restrict__ adj,
            const float* __restrict__ b2, float* __restrict__ out)
{
    __shared__ float fv[64][NCLS];   // 4 KB
    __shared__ float pvs[16][72];
    __shared__ float nbs[64];
    const int t = threadIdx.x;
    const int R0 = blockIdx.x * 16;
    const int r = t >> 4, c = t & 15;
    const int row = R0 + r;
    const float s_r = s2[row];
    const int* adjp = adj + (size_t)row * NN;

    float m = -INFINITY, l = 0.f, acc = 0.f;

    for (int j0 = 0; j0 < NN; j0 += 64) {
        if (t < 64) nbs[t] = nb2[j0 + t];
        ((float4*)&fv[0][0])[t] = ((const float4*)(feats2 + (size_t)j0 * NCLS))[t];
        __syncthreads();

        const int4 av = *(const int4*)(adjp + j0 + c * 4);
        const float v0 = (av.x > 0) ? leaky(s_r + nbs[c * 4 + 0]) : MASK_VAL;
        const float v1 = (av.y > 0) ? leaky(s_r + nbs[c * 4 + 1]) : MASK_VAL;
        const float v2 = (av.z > 0) ? leaky(s_r + nbs[c * 4 + 2]) : MASK_VAL;
        const float v3 = (av.w > 0) ? leaky(s_r + nbs[c * 4 + 3]) : MASK_VAL;

        float cmax = fmaxf(fmaxf(v0, v1), fmaxf(v2, v3));
        #pragma unroll
        for (int off = 8; off > 0; off >>= 1) cmax = fmaxf(cmax, __shfl_xor(cmax, off, 64));
        const float nm = fmaxf(m, cmax);
        const float alpha = __expf(m - nm);
        const float p0 = __expf(v0 - nm), p1 = __expf(v1 - nm);
        const float p2 = __expf(v2 - nm), p3 = __expf(v3 - nm);
        float cs = p0 + p1 + p2 + p3;
        #pragma unroll
        for (int off = 8; off > 0; off >>= 1) cs += __shfl_xor(cs, off, 64);
        l = l * alpha + cs;
        m = nm;
        acc *= alpha;
        *(float4*)&pvs[r][c * 4] = make_float4(p0, p1, p2, p3);
        __syncthreads();

        #pragma unroll 16
        for (int jj = 0; jj < 64; ++jj) acc += pvs[r][jj] * fv[jj][c];
        __syncthreads();
    }

    const float v = fmaxf(acc / l + b2[c], 0.f);
    float mx = v;
    #pragma unroll
    for (int off = 8; off > 0; off >>= 1) mx = fmaxf(mx, __shfl_xor(mx, off, 64));
    const float e = __expf(v - mx);
    float se = e;
    #pragma unroll
    for (int off = 8; off > 0; off >>= 1) se += __shfl_xor(se, off, 64);
    out[row * NCLS + c] = v - mx - __logf(se);
}

// ---------------------------------------------------------------------------
extern "C" void kernel_launch(void* const* d_in, const int* in_sizes, int n_in,
                              void* d_out, int out_size, void* d_ws, size_t ws_size,
                              hipStream_t stream)
{
    const float* x   = (const float*)d_in[0];
    const int*   adj = (const int*)  d_in[1];
    const float* W1  = (const float*)d_in[2];
    const float* b1  = (const float*)d_in[3];
    const float* as1 = (const float*)d_in[4];
    const float* an1 = (const float*)d_in[5];
    const float* W2  = (const float*)d_in[6];
    const float* b2  = (const float*)d_in[7];
    const float* as2 = (const float*)d_in[8];
    const float* an2 = (const float*)d_in[9];
    float* out = (float*)d_out;

    float* ws = (float*)d_ws;
    float* feats1 = ws;                                   // 8*4096*64
    float* s1     = feats1 + (size_t)H1 * NN * NHID;      // 8*4096
    float* nb1    = s1 + (size_t)H1 * NN;                 // 8*4096
    float* hcat   = nb1 + (size_t)H1 * NN;                // 4096*512
    float* feats2 = hcat + (size_t)NN * (H1 * NHID);      // 4096*16
    float* s2v    = feats2 + (size_t)NN * NCLS;           // 4096
    float* nb2v   = s2v + NN;                             // 4096

    k_feats1<<<dim3(NN / 16, H1), 256, 0, stream>>>(x, W1, as1, an1, feats1, s1, nb1);
    k_gat1  <<<dim3(NN / 16, H1), 256, 0, stream>>>(feats1, s1, nb1, adj, b1, hcat);
    k_feats2<<<dim3(NN / 16),     256, 0, stream>>>(hcat, W2, as2, an2, feats2, s2v, nb2v);
    k_gat2  <<<dim3(NN / 16),     256, 0, stream>>>(feats2, s2v, nb2v, adj, b2, out);
}

// Round 2
// 289.305 us; speedup vs baseline: 2.8325x; 2.8325x over previous
//
#include <hip/hip_runtime.h>

#define NN 4096
#define NFEAT 512
#define NHID 64
#define H1 8
#define NCLS 16
#define NEG_SLOPE 0.2f
#define VSTR 88   // bf16 elements per vT row: 176B rows, 16B aligned, conflict-free

typedef short bf16x8 __attribute__((ext_vector_type(8)));
typedef float f32x4 __attribute__((ext_vector_type(4)));

__device__ __forceinline__ unsigned short f2bf(float f) {
    unsigned u = __float_as_uint(f);
    u += 0x7fffu + ((u >> 16) & 1u);          // round-to-nearest-even
    return (unsigned short)(u >> 16);
}
__device__ __forceinline__ float leaky(float v) { return fmaxf(v, NEG_SLOPE * v); }

// ---------------------------------------------------------------------------
// Pack adj (int32 0/1) into bitmask: bits[row][w] covers j = w*64..w*64+63
// ---------------------------------------------------------------------------
__global__ __launch_bounds__(256)
void k_pack(const int* __restrict__ adj, unsigned long long* __restrict__ bits)
{
    const int row = blockIdx.x;
    const int t = threadIdx.x, wv = t >> 6, lane = t & 63;
    const int* ap = adj + (size_t)row * NN;
    for (int w = wv; w < 64; w += 4) {
        unsigned long long m = __ballot(ap[w * 64 + lane] > 0);
        if (lane == 0) bits[(size_t)row * 64 + w] = m;
    }
}

// ---------------------------------------------------------------------------
// Kernel A: feats1 (bf16 out) + s1/nb1 (fp32). grid (256,8), 256 thr.
// ---------------------------------------------------------------------------
__global__ __launch_bounds__(256)
void k_feats1(const float* __restrict__ x, const float* __restrict__ W1,
              const float* __restrict__ as1, const float* __restrict__ an1,
              unsigned short* __restrict__ f1b, float* __restrict__ s1,
              float* __restrict__ nb1)
{
    __shared__ float xs[16][NFEAT];
    __shared__ float fs[16][NHID];
    const int t = threadIdx.x;
    const int rt = blockIdx.x, h = blockIdx.y;
    const int R0 = rt * 16;

    {
        const float4* xg = (const float4*)(x + (size_t)R0 * NFEAT);
        float4* xl = (float4*)&xs[0][0];
        #pragma unroll
        for (int i = 0; i < 8; ++i) xl[t + 256 * i] = xg[t + 256 * i];
    }
    __syncthreads();

    const int c  = t & 63;
    const int wv = t >> 6;
    const int r0 = wv * 4;
    const float* Wp = W1 + ((size_t)h * NFEAT) * NHID + c;
    float a0 = 0.f, a1 = 0.f, a2 = 0.f, a3 = 0.f;
    for (int k = 0; k < NFEAT; k += 4) {
        const float w0 = Wp[(k + 0) * NHID];
        const float w1 = Wp[(k + 1) * NHID];
        const float w2 = Wp[(k + 2) * NHID];
        const float w3 = Wp[(k + 3) * NHID];
        const float4 x0 = *(const float4*)&xs[r0 + 0][k];
        const float4 x1 = *(const float4*)&xs[r0 + 1][k];
        const float4 x2 = *(const float4*)&xs[r0 + 2][k];
        const float4 x3 = *(const float4*)&xs[r0 + 3][k];
        a0 += x0.x * w0 + x0.y * w1 + x0.z * w2 + x0.w * w3;
        a1 += x1.x * w0 + x1.y * w1 + x1.z * w2 + x1.w * w3;
        a2 += x2.x * w0 + x2.y * w1 + x2.z * w2 + x2.w * w3;
        a3 += x3.x * w0 + x3.y * w1 + x3.z * w2 + x3.w * w3;
    }
    unsigned short* fb = f1b + ((size_t)h * NN + R0 + r0) * NHID + c;
    fb[0 * NHID] = f2bf(a0); fb[1 * NHID] = f2bf(a1);
    fb[2 * NHID] = f2bf(a2); fb[3 * NHID] = f2bf(a3);
    fs[r0 + 0][c] = a0; fs[r0 + 1][c] = a1; fs[r0 + 2][c] = a2; fs[r0 + 3][c] = a3;
    __syncthreads();

    const float vas = as1[h * NHID + c];
    const float van = an1[h * NHID + c];
    for (int rr = wv; rr < 16; rr += 4) {
        const float f = fs[rr][c];
        float ps = f * vas, pn = f * van;
        #pragma unroll
        for (int off = 32; off > 0; off >>= 1) {
            ps += __shfl_xor(ps, off, 64);
            pn += __shfl_xor(pn, off, 64);
        }
        if (c == 0) { s1[h * NN + R0 + rr] = ps; nb1[h * NN + R0 + rr] = pn; }
    }
}

// ---------------------------------------------------------------------------
// Per-block max over cnt floats: dst[b] = max(src[b*cnt .. +cnt])
// ---------------------------------------------------------------------------
__global__ __launch_bounds__(256)
void k_colmax(const float* __restrict__ src, float* __restrict__ dst, int cnt)
{
    const int b = blockIdx.x, t = threadIdx.x;
    const float* p = src + (size_t)b * cnt;
    float m = -INFINITY;
    for (int i = t; i < cnt; i += 256) m = fmaxf(m, p[i]);
    #pragma unroll
    for (int off = 32; off > 0; off >>= 1) m = fmaxf(m, __shfl_xor(m, off, 64));
    __shared__ float sm[4];
    if ((t & 63) == 0) sm[t >> 6] = m;
    __syncthreads();
    if (t == 0) dst[b] = fmaxf(fmaxf(sm[0], sm[1]), fmaxf(sm[2], sm[3]));
}

// ---------------------------------------------------------------------------
// Kernel B: MFMA masked-softmax aggregation, layer 1.
// Block: 256 thr = 4 waves, 64 rows (wave w -> rows R0+16w..+15). grid (64,8).
// Fixed-max softmax: p = adj ? exp(leaky(s+nb) - mhat) : 0; no online state.
// A-frag (P) built in registers; B-frag (V^T) from conflict-free LDS tile.
// ---------------------------------------------------------------------------
__global__ __launch_bounds__(256)
void k_gat1(const unsigned short* __restrict__ f1b, const float* __restrict__ s1,
            const float* __restrict__ nb1, const unsigned long long* __restrict__ abits,
            const float* __restrict__ b1, const float* __restrict__ nbmax1,
            float* __restrict__ hcat)
{
    __shared__ __align__(16) unsigned short vT[64 * VSTR];   // 11264 B
    const int t = threadIdx.x, wv = t >> 6, lane = t & 63;
    const int q = lane >> 4, n = lane & 15;
    const int h = blockIdx.y;
    const int R0 = blockIdx.x * 64;
    const int myrow = R0 + wv * 16 + n;                      // A-frag row
    const float s_r = s1[h * NN + myrow];
    const float mhat = leaky(s_r + nbmax1[h]);
    const unsigned long long* arow = abits + (size_t)myrow * 64;
    const unsigned short* fbase = f1b + (size_t)h * NN * NHID;
    const float* nbp = nb1 + (size_t)h * NN;

    const int sc = t & 63;        // staging: this thread owns column sc
    const int soct = t >> 6;      // j-octets soct, soct+4

    f32x4 acc[4] = {{0.f,0.f,0.f,0.f},{0.f,0.f,0.f,0.f},
                    {0.f,0.f,0.f,0.f},{0.f,0.f,0.f,0.f}};
    float lsum = 0.f;

    for (int j0 = 0; j0 < NN; j0 += 64) {
        // ---- stage transposed bf16 V-tile: vT[c][j] = feats[j0+j][c] ----
        #pragma unroll
        for (int it = 0; it < 2; ++it) {
            const int oc = soct + it * 4;                    // j-octet 0..7
            const unsigned short* src = fbase + (size_t)(j0 + oc * 8) * NHID + sc;
            const unsigned e0 = src[0 * NHID], e1 = src[1 * NHID];
            const unsigned e2 = src[2 * NHID], e3 = src[3 * NHID];
            const unsigned e4 = src[4 * NHID], e5 = src[5 * NHID];
            const unsigned e6 = src[6 * NHID], e7 = src[7 * NHID];
            int4 w;
            w.x = (int)(e0 | (e1 << 16));
            w.y = (int)(e2 | (e3 << 16));
            w.z = (int)(e4 | (e5 << 16));
            w.w = (int)(e6 | (e7 << 16));
            *(int4*)&vT[sc * VSTR + oc * 8] = w;
        }
        __syncthreads();

        const unsigned long long a64 = arow[j0 >> 6];
        #pragma unroll
        for (int ch = 0; ch < 2; ++ch) {
            const int kb = ch * 32 + q * 8;                  // this lane's j-window
            const float4 nba = *(const float4*)(nbp + j0 + kb);
            const float4 nbb = *(const float4*)(nbp + j0 + kb + 4);
            const unsigned bits8 = (unsigned)(a64 >> kb) & 0xffu;
            const float nbv[8] = {nba.x, nba.y, nba.z, nba.w,
                                  nbb.x, nbb.y, nbb.z, nbb.w};
            bf16x8 af;
            #pragma unroll
            for (int j = 0; j < 8; ++j) {
                const float v = leaky(s_r + nbv[j]);
                const float e = ((bits8 >> j) & 1u) ? __expf(v - mhat) : 0.f;
                lsum += e;
                af[j] = (short)f2bf(e);
            }
            #pragma unroll
            for (int nt = 0; nt < 4; ++nt) {
                const bf16x8 bf = *(const bf16x8*)&vT[(nt * 16 + n) * VSTR + kb];
                acc[nt] = __builtin_amdgcn_mfma_f32_16x16x32_bf16(af, bf, acc[nt], 0, 0, 0);
            }
        }
        __syncthreads();
    }

    lsum += __shfl_xor(lsum, 16, 64);
    lsum += __shfl_xor(lsum, 32, 64);   // full l for row (lane&15)

    #pragma unroll
    for (int i = 0; i < 4; ++i) {
        const float li = __shfl(lsum, q * 4 + i, 64);        // l for D-row q*4+i
        const float inv = 1.f / li;
        const int row = R0 + wv * 16 + q * 4 + i;
        float* op = hcat + (size_t)row * (H1 * NHID) + h * NHID;
        #pragma unroll
        for (int nt = 0; nt < 4; ++nt) {
            const float bv = b1[h * NHID + nt * 16 + n];
            op[nt * 16 + n] = fmaxf(acc[nt][i] * inv + bv, 0.f);  // relu; elu(x>=0)=x
        }
    }
}

// ---------------------------------------------------------------------------
// Kernel C1: feats2 = hcat @ W2 (bf16 out) + s2/nb2. grid 256, 256 thr.
// ---------------------------------------------------------------------------
__global__ __launch_bounds__(256)
void k_feats2(const float* __restrict__ hcat, const float* __restrict__ W2,
              const float* __restrict__ as2, const float* __restrict__ an2,
              unsigned short* __restrict__ f2b, float* __restrict__ s2,
              float* __restrict__ nb2)
{
    __shared__ float hs[16][520];
    __shared__ float w2s[NFEAT][NCLS];
    __shared__ float fs2[16][NCLS];
    const int t = threadIdx.x;
    const int R0 = blockIdx.x * 16;

    {
        const float4* hg = (const float4*)(hcat + (size_t)R0 * (H1 * NHID));
        #pragma unroll
        for (int i = 0; i < 8; ++i) {
            const int idx = t + 256 * i;
            const int rr = idx >> 7, col = idx & 127;
            *(float4*)&hs[rr][col * 4] = hg[idx];
        }
        const float4* wg = (const float4*)W2;
        float4* wl = (float4*)&w2s[0][0];
        #pragma unroll
        for (int i = 0; i < 8; ++i) wl[t + 256 * i] = wg[t + 256 * i];
    }
    __syncthreads();

    const int r = t >> 4, c = t & 15;
    float acc = 0.f;
    #pragma unroll 8
    for (int k = 0; k < NFEAT; ++k) acc += hs[r][k] * w2s[k][c];
    f2b[(size_t)(R0 + r) * NCLS + c] = f2bf(acc);
    fs2[r][c] = acc;
    __syncthreads();

    if (t < 16) {
        float ss = 0.f, sn = 0.f;
        #pragma unroll
        for (int cc = 0; cc < NCLS; ++cc) { ss += fs2[t][cc] * as2[cc]; sn += fs2[t][cc] * an2[cc]; }
        s2[R0 + t] = ss; nb2[R0 + t] = sn;
    }
}

// ---------------------------------------------------------------------------
// Kernel C2: MFMA aggregation layer 2 + relu + log_softmax. grid 256, 256 thr.
// Block = 16 rows; each wave covers a disjoint quarter of j (no barriers in
// the loop — fixed-max softmax partials combine additively at the end).
// ---------------------------------------------------------------------------
__global__ __launch_bounds__(256)
void k_gat2(const unsigned short* __restrict__ f2b, const float* __restrict__ s2,
            const float* __restrict__ nb2, const unsigned long long* __restrict__ abits,
            const float* __restrict__ b2, const float* __restrict__ nbmax2,
            float* __restrict__ out)
{
    __shared__ __align__(16) unsigned short vT2[4][16 * VSTR];  // per-wave tiles
    __shared__ float cmb[4][16][16];
    __shared__ float lw[4][16];
    const int t = threadIdx.x, wv = t >> 6, lane = t & 63;
    const int q = lane >> 4, n = lane & 15;
    const int R0 = blockIdx.x * 16;
    const int myrow = R0 + n;
    const float s_r = s2[myrow];
    const float mhat = leaky(s_r + nbmax2[0]);
    const unsigned long long* arow = abits + (size_t)myrow * 64;

    const int sc = lane & 15, sob = lane >> 4;   // staging: column, j-octet base
    unsigned short* myT = vT2[wv];

    f32x4 acc = {0.f, 0.f, 0.f, 0.f};
    float lsum = 0.f;

    for (int jb = 0; jb < 16; ++jb) {
        const int j0 = wv * 64 + jb * 256;
        #pragma unroll
        for (int it = 0; it < 2; ++it) {
            const int oc = sob + it * 4;
            const unsigned short* src = f2b + (size_t)(j0 + oc * 8) * NCLS + sc;
            const unsigned e0 = src[0 * NCLS], e1 = src[1 * NCLS];
            const unsigned e2 = src[2 * NCLS], e3 = src[3 * NCLS];
            const unsigned e4 = src[4 * NCLS], e5 = src[5 * NCLS];
            const unsigned e6 = src[6 * NCLS], e7 = src[7 * NCLS];
            int4 w;
            w.x = (int)(e0 | (e1 << 16));
            w.y = (int)(e2 | (e3 << 16));
            w.z = (int)(e4 | (e5 << 16));
            w.w = (int)(e6 | (e7 << 16));
            *(int4*)&myT[sc * VSTR + oc * 8] = w;
        }
        // same-wave LDS RAW: compiler inserts lgkmcnt wait; no barrier needed
        const unsigned long long a64 = arow[j0 >> 6];
        #pragma unroll
        for (int ch = 0; ch < 2; ++ch) {
            const int kb = ch * 32 + q * 8;
            const float4 nba = *(const float4*)(nb2 + j0 + kb);
            const float4 nbb = *(const float4*)(nb2 + j0 + kb + 4);
            const unsigned bits8 = (unsigned)(a64 >> kb) & 0xffu;
            const float nbv[8] = {nba.x, nba.y, nba.z, nba.w,
                                  nbb.x, nbb.y, nbb.z, nbb.w};
            bf16x8 af;
            #pragma unroll
            for (int j = 0; j < 8; ++j) {
                const float v = leaky(s_r + nbv[j]);
                const float e = ((bits8 >> j) & 1u) ? __expf(v - mhat) : 0.f;
                lsum += e;
                af[j] = (short)f2bf(e);
            }
            const bf16x8 bf = *(const bf16x8*)&myT[n * VSTR + kb];
            acc = __builtin_amdgcn_mfma_f32_16x16x32_bf16(af, bf, acc, 0, 0, 0);
        }
    }

    lsum += __shfl_xor(lsum, 16, 64);
    lsum += __shfl_xor(lsum, 32, 64);
    #pragma unroll
    for (int i = 0; i < 4; ++i) cmb[wv][q * 4 + i][n] = acc[i];
    if (lane < 16) lw[wv][lane] = lsum;
    __syncthreads();

    const int r = t >> 4, c = t & 15;
    const float tot = cmb[0][r][c] + cmb[1][r][c] + cmb[2][r][c] + cmb[3][r][c];
    const float lt  = lw[0][r] + lw[1][r] + lw[2][r] + lw[3][r];
    float val = fmaxf(tot / lt + b2[c], 0.f);
    float mx = val;
    #pragma unroll
    for (int off = 1; off < 16; off <<= 1) mx = fmaxf(mx, __shfl_xor(mx, off, 64));
    const float e = __expf(val - mx);
    float se = e;
    #pragma unroll
    for (int off = 1; off < 16; off <<= 1) se += __shfl_xor(se, off, 64);
    out[(size_t)(R0 + r) * NCLS + c] = val - mx - __logf(se);
}

// ---------------------------------------------------------------------------
extern "C" void kernel_launch(void* const* d_in, const int* in_sizes, int n_in,
                              void* d_out, int out_size, void* d_ws, size_t ws_size,
                              hipStream_t stream)
{
    const float* x   = (const float*)d_in[0];
    const int*   adj = (const int*)  d_in[1];
    const float* W1  = (const float*)d_in[2];
    const float* b1  = (const float*)d_in[3];
    const float* as1 = (const float*)d_in[4];
    const float* an1 = (const float*)d_in[5];
    const float* W2  = (const float*)d_in[6];
    const float* b2  = (const float*)d_in[7];
    const float* as2 = (const float*)d_in[8];
    const float* an2 = (const float*)d_in[9];
    float* out = (float*)d_out;

    char* ws = (char*)d_ws;
    unsigned long long* abits = (unsigned long long*)ws;        // 2 MB
    unsigned short* f1b = (unsigned short*)(ws + (2u << 20));   // 4 MB
    float* s1   = (float*)(ws + (6u << 20));                    // 128 KB
    float* nb1  = (float*)(ws + (6u << 20) + (128u << 10));     // 128 KB
    float* hcat = (float*)(ws + (6u << 20) + (256u << 10));     // 8 MB
    unsigned short* f2b = (unsigned short*)(ws + (14u << 20) + (256u << 10)); // 128 KB
    float* s2   = (float*)(ws + (14u << 20) + (384u << 10));    // 16 KB
    float* nb2  = (float*)(ws + (14u << 20) + (400u << 10));    // 16 KB
    float* nbmax1 = (float*)(ws + (14u << 20) + (416u << 10));  // 32 B
    float* nbmax2 = nbmax1 + 8;

    k_pack  <<<dim3(NN),         256, 0, stream>>>(adj, abits);
    k_feats1<<<dim3(NN / 16, H1), 256, 0, stream>>>(x, W1, as1, an1, f1b, s1, nb1);
    k_colmax<<<dim3(H1),         256, 0, stream>>>(nb1, nbmax1, NN);
    k_gat1  <<<dim3(NN / 64, H1), 256, 0, stream>>>(f1b, s1, nb1, abits, b1, nbmax1, hcat);
    k_feats2<<<dim3(NN / 16),    256, 0, stream>>>(hcat, W2, as2, an2, f2b, s2, nb2);
    k_colmax<<<dim3(1),          256, 0, stream>>>(nb2, nbmax2, NN);
    k_gat2  <<<dim3(NN / 16),    256, 0, stream>>>(f2b, s2, nb2, abits, b2, nbmax2, out);
}